// Round 1
// baseline (374.591 us; speedup 1.0000x reference)
//
#include <hip/hip_runtime.h>
#include <cstdint>
#include <cstddef>

// ---------------- problem constants ----------------
#define NTOK 16384          // 8*2048 tokens
#define DIM  512
#define KCB  8192           // codebook entries
#define MARGIN 6.0e-3f      // > worst-case bf16 screening error (validated R1-R5)
#define LISTCAP 512         // max tokens per code

typedef short s16x8 __attribute__((ext_vector_type(8)));   // 8 bf16 in 4 VGPRs
typedef float f32x4 __attribute__((ext_vector_type(4)));

// ---------------- workspace layout (bytes) ----------------
static const size_t WS_XN   = 0;           // ushort[NTOK*DIM]   bf16 normalized x  -> 16777216
static const size_t WS_WN   = 16777216;    // ushort[KCB*DIM]    bf16 normalized w  -> 25165824
static const size_t WS_KV   = 25165824;    // uint2[NTOK*64]     packed top2 keys   -> 33554432
static const size_t WS_LP   = 37748736;    // float[NTOK]        loss partials      -> 37814272
static const size_t WS_PRE  = 37814272;    // float[KCB]         pre-smoothing cs   -> 37847040
static const size_t WS_N    = 37847040;    // double             n (256B pad)       -> 37847296
static const size_t WS_CNT  = 37847296;    // int[KCB]           counts (zeroed)    -> 37880064
static const size_t WS_LIST = 37880064;    // int[KCB*LISTCAP]   token lists        -> 54657280

// ---------------- helpers ----------------
__device__ __forceinline__ void gl_lds16(const void* g, void* l) {
  __builtin_amdgcn_global_load_lds(
      (__attribute__((address_space(1))) void*)(uintptr_t)g,
      (__attribute__((address_space(3))) void*)(uint32_t)(uintptr_t)l,
      16, 0, 0);
}

__device__ __forceinline__ unsigned short f2bf(float f) {
  unsigned int u = __float_as_uint(f);
  u = (u + 0x7fffu + ((u >> 16) & 1u)) >> 16;   // RNE
  return (unsigned short)u;
}

// ---------------- K1: l2-normalize x and w rows into bf16 ----------------
__global__ __launch_bounds__(256) void k_normalize(const float* __restrict__ x,
                                                   const float* __restrict__ w,
                                                   unsigned short* __restrict__ xn,
                                                   unsigned short* __restrict__ wn) {
  const int row = blockIdx.x;
  const int tid = threadIdx.x, lane = tid & 63, wave = tid >> 6;
  const float* src;
  unsigned short* dst;
  if (row < NTOK) { src = x + (size_t)row * DIM;          dst = xn + (size_t)row * DIM; }
  else            { src = w + (size_t)(row - NTOK) * DIM; dst = wn + (size_t)(row - NTOK) * DIM; }
  const int e = tid * 2;
  float2 v = *(const float2*)(src + e);
  float ss = v.x * v.x + v.y * v.y;
  #pragma unroll
  for (int off = 32; off > 0; off >>= 1) ss += __shfl_xor(ss, off);
  __shared__ float red[4];
  if (lane == 0) red[wave] = ss;
  __syncthreads();
  const float s = red[0] + red[1] + red[2] + red[3];
  const float inv = rsqrtf(s + 1e-12f);
  unsigned int lo = f2bf(v.x * inv), hi = f2bf(v.y * inv);
  *(unsigned int*)(dst + e) = lo | (hi << 16);
}

// ---------------- K2: 256x256 8-phase bf16 MFMA GEMM (T3+T4+T5 on top of T2) ----------------
// 512 threads = 8 waves (4M x 2N), per-wave 64m x 128n output (same as previous kernel ->
// epilogue / kv layout / k_select unchanged).  BK=64, LDS 128 KiB double-buffered.
// Schedule: per window t (one K-tile), 4 phases x {ds_read ; stage 1 half-tile ;
// s_barrier ; lgkmcnt(0) ; setprio(1) ; 16 MFMA ; setprio(0) ; s_barrier}.
// All af (both K-halves) read at q0 -> A-halves retire after q0, so:
//   q0: stage B0(t+1)  q1: stage B1(t+1)   (other buffer; its reads ended window t-1)
//   q2: stage A0(t+2)  q3: stage A1(t+2)   (current buffer; A reads ended at q0)
// One counted vmcnt(4) per window (never 0 in steady state): leaves the 2 newest A
// half-tiles (4 loads) in flight, guarantees B(t+1)/A(t+1) landed before window t+1.
#define SBAR()  asm volatile("s_barrier" ::: "memory")
#define LGKM0() do { asm volatile("s_waitcnt lgkmcnt(0)" ::: "memory"); \
                     __builtin_amdgcn_sched_barrier(0); } while (0)
#define VMW(N)  asm volatile("s_waitcnt vmcnt(" #N ")" ::: "memory")

__global__ __launch_bounds__(512, 2) void k_gemm_top2(const unsigned short* __restrict__ xn,
                                                      const unsigned short* __restrict__ wn,
                                                      uint2* __restrict__ kv) {
  __shared__ __align__(16) char lds[131072];      // A: 2 bufs x 32KB | B: 2 bufs x 32KB
  char* const ldsA = lds;
  char* const ldsB = lds + 65536;
  const int tid = threadIdx.x, wave = tid >> 6, lane = tid & 63;
  const int quad = lane >> 4, col = lane & 15;
  const int wave_m = (wave & 3) * 64;             // 4 M-waves
  const int wave_n = (wave >> 2) * 128;           // 2 N-waves
  const int n0 = blockIdx.x * 256, m0 = blockIdx.y * 256;

  // staging per-thread constants: two 16B segments per half-tile (128 rows x 64 cols)
  const int seg0 = wave * 128 + lane;             // 0..1023
  const int r0 = seg0 >> 3, cg0 = (seg0 & 7) ^ (r0 & 7);
  const int seg1 = seg0 + 64;
  const int r1 = seg1 >> 3, cg1 = (seg1 & 7) ^ (r1 & 7);
  const unsigned short* const pA0 = xn + (size_t)(m0 + r0) * DIM + cg0 * 8;
  const unsigned short* const pA1 = xn + (size_t)(m0 + r1) * DIM + cg1 * 8;
  const unsigned short* const pB0 = wn + (size_t)(n0 + r0) * DIM + cg0 * 8;
  const unsigned short* const pB1 = wn + (size_t)(n0 + r1) * DIM + cg1 * 8;
  const int dj0 = wave * 2048;                    // per-wave linear LDS dest (HW adds lane*16)

#define STAGE_A(HALF, KT) do { \
    char* da_ = ldsA + (((KT) & 1) << 15) + ((HALF) << 14) + dj0; \
    gl_lds16(pA0 + (HALF) * 65536 + (KT) * 64, da_); \
    gl_lds16(pA1 + (HALF) * 65536 + (KT) * 64, da_ + 1024); \
  } while (0)
#define STAGE_B(HALF, KT) do { \
    char* db_ = ldsB + (((KT) & 1) << 15) + ((HALF) << 14) + dj0; \
    gl_lds16(pB0 + (HALF) * 65536 + (KT) * 64, db_); \
    gl_lds16(pB1 + (HALF) * 65536 + (KT) * 64, db_ + 1024); \
  } while (0)

  // read offsets (bytes within one buffer); kbi=1 = XOR 64 (flips K-group bit2)
  int offA[4], offB[8];
  #pragma unroll
  for (int mi = 0; mi < 4; ++mi) {
    int row = wave_m + mi * 16 + col;
    offA[mi] = (row >> 7) * 16384 + (row & 127) * 128 + ((quad ^ (row & 7)) * 16);
  }
  #pragma unroll
  for (int ni = 0; ni < 8; ++ni) {
    int row = wave_n + ni * 16 + col;
    offB[ni] = (row >> 7) * 16384 + (row & 127) * 128 + ((quad ^ (row & 7)) * 16);
  }

  f32x4 acc[4][8] = {};
  s16x8 af[4][2];

#define PHASE(KBI, NB, STAGE_STMT, TAIL_STMT) do {                                   \
    s16x8 bfr0 = *(const s16x8*)(ldsB + bufoff + (offB[(NB) + 0] ^ ((KBI) * 64)));   \
    s16x8 bfr1 = *(const s16x8*)(ldsB + bufoff + (offB[(NB) + 1] ^ ((KBI) * 64)));   \
    s16x8 bfr2 = *(const s16x8*)(ldsB + bufoff + (offB[(NB) + 2] ^ ((KBI) * 64)));   \
    s16x8 bfr3 = *(const s16x8*)(ldsB + bufoff + (offB[(NB) + 3] ^ ((KBI) * 64)));   \
    STAGE_STMT;                                                                      \
    SBAR();                                                                          \
    LGKM0();                                                                         \
    __builtin_amdgcn_s_setprio(1);                                                   \
    _Pragma("unroll")                                                                \
    for (int mi = 0; mi < 4; ++mi) {                                                 \
      acc[mi][(NB) + 0] = __builtin_amdgcn_mfma_f32_16x16x32_bf16(af[mi][KBI], bfr0, acc[mi][(NB) + 0], 0, 0, 0); \
      acc[mi][(NB) + 1] = __builtin_amdgcn_mfma_f32_16x16x32_bf16(af[mi][KBI], bfr1, acc[mi][(NB) + 1], 0, 0, 0); \
      acc[mi][(NB) + 2] = __builtin_amdgcn_mfma_f32_16x16x32_bf16(af[mi][KBI], bfr2, acc[mi][(NB) + 2], 0, 0, 0); \
      acc[mi][(NB) + 3] = __builtin_amdgcn_mfma_f32_16x16x32_bf16(af[mi][KBI], bfr3, acc[mi][(NB) + 3], 0, 0, 0); \
    }                                                                                \
    __builtin_amdgcn_s_setprio(0);                                                   \
    TAIL_STMT;                                                                       \
    SBAR();                                                                          \
  } while (0)

  // prologue: K-tile 0 (A+B) + A of K-tile 1 in flight; allow A(1)'s 4 loads outstanding
  STAGE_A(0, 0); STAGE_A(1, 0); STAGE_B(0, 0); STAGE_B(1, 0);
  STAGE_A(0, 1); STAGE_A(1, 1);
  VMW(4);
  SBAR();

  #pragma unroll 1
  for (int t = 0; t < 8; ++t) {
    const int bufoff = (t & 1) << 15;
    #pragma unroll
    for (int mi = 0; mi < 4; ++mi) {              // all af early -> A-halves retire at q0
      af[mi][0] = *(const s16x8*)(ldsA + bufoff + offA[mi]);
      af[mi][1] = *(const s16x8*)(ldsA + bufoff + (offA[mi] ^ 64));
    }
    PHASE(0, 0, if (t < 7) STAGE_B(0, t + 1), );
    PHASE(0, 4, if (t < 7) STAGE_B(1, t + 1), );
    PHASE(1, 0, if (t < 6) STAGE_A(0, t + 2), );
    PHASE(1, 4, if (t < 6) STAGE_A(1, t + 2),
          if (t < 6) { VMW(4); } else if (t == 6) { VMW(0); });
  }

#undef PHASE
#undef STAGE_A
#undef STAGE_B

  // -------- epilogue: packed-key top2 over this wave's 128 codes (unchanged) --------
  const int tile = blockIdx.x * 2 + (wave >> 2);
  unsigned int rk1 = 0, rk2 = 0;
  #pragma unroll
  for (int mi = 0; mi < 4; ++mi) {
    #pragma unroll
    for (int r = 0; r < 4; ++r) {
      const int p = mi * 4 + r;
      unsigned int k1 = 0, k2 = 0;
      #pragma unroll
      for (int ni = 0; ni < 8; ++ni) {
        float vb = acc[mi][ni][r] + 2.0f;                 // biased positive -> uint order == float order
        unsigned int key = (__float_as_uint(vb) & ~0x7Fu) | (unsigned int)(ni * 16 + col);
        unsigned int mn = min(k1, key);
        k1 = max(k1, key);
        k2 = max(k2, mn);
      }
      #pragma unroll
      for (int off = 1; off < 16; off <<= 1) {
        unsigned int o1 = (unsigned int)__shfl_xor((int)k1, off);
        unsigned int o2 = (unsigned int)__shfl_xor((int)k2, off);
        unsigned int mn = min(k1, o1);
        k1 = max(k1, o1);
        k2 = max(max(k2, o2), mn);
      }
      if (col == p) { rk1 = k1; rk2 = k2; }               // lane-compact
    }
  }
  const int row = wave_m + (col >> 2) * 16 + quad * 4 + (col & 3);  // bijective over 64
  kv[(size_t)(m0 + row) * 64 + tile] = make_uint2(rk1, rk2);
}

// ---------------- K3: exact fp64 rescore -> idx, fused gather + loss + list ----------------
// 256 threads = 4 waves, one token per wave
__global__ __launch_bounds__(256) void k_select(const float* __restrict__ x,
                                                const float* __restrict__ wgt,
                                                const uint2* __restrict__ kv,
                                                float* __restrict__ out0,
                                                float* __restrict__ out_idx,
                                                float* __restrict__ lp,
                                                int* __restrict__ cnt,
                                                int* __restrict__ list) {
  const int wave = threadIdx.x >> 6, lane = threadIdx.x & 63;
  const int t = blockIdx.x * 4 + wave;

  const uint2 kp = kv[(size_t)t * 64 + lane];
  const float v1 = __uint_as_float(kp.x);     // biased (+2.0), index bits add <=3e-5
  const float v2 = __uint_as_float(kp.y);
  const int   i1 = lane * 128 + (int)(kp.x & 0x7Fu);

  float gm = v1;
  #pragma unroll
  for (int off = 32; off > 0; off >>= 1) gm = fmaxf(gm, __shfl_xor(gm, off));
  const float thresh = gm - MARGIN;

  unsigned long long m1 = __ballot(v1 >= thresh);
  unsigned long long m2 = __ballot(v2 >= thresh);

  const float* xrow = x + (size_t)t * DIM;
  const float* xr = xrow + lane * 8;
  float4 x0 = *(const float4*)xr;
  float4 x1 = *(const float4*)(xr + 4);
  double xv[8] = {x0.x, x0.y, x0.z, x0.w, x1.x, x1.y, x1.z, x1.w};

  double bestv = -1e300; int besti = 1 << 30;   // per-lane running best

  // wave-collective exact eval (result uniform across lanes)
  auto evalc = [&](int c) {
    const float* wr = wgt + (size_t)c * DIM + lane * 8;
    float4 w0 = *(const float4*)wr;
    float4 w1 = *(const float4*)(wr + 4);
    double s  = (double)w0.x * xv[0] + (double)w0.y * xv[1] + (double)w0.z * xv[2] + (double)w0.w * xv[3]
              + (double)w1.x * xv[4] + (double)w1.y * xv[5] + (double)w1.z * xv[6] + (double)w1.w * xv[7];
    double nw = (double)w0.x * w0.x + (double)w0.y * w0.y + (double)w0.z * w0.z + (double)w0.w * w0.w
              + (double)w1.x * w1.x + (double)w1.y * w1.y + (double)w1.z * w1.z + (double)w1.w * w1.w;
    #pragma unroll
    for (int off = 1; off < 64; off <<= 1) { s += __shfl_xor(s, off); nw += __shfl_xor(nw, off); }
    double sim = s / sqrt(nw + 1e-12);      // x-norm omitted: constant per token
    if (sim > bestv || (sim == bestv && c < besti)) { bestv = sim; besti = c; }
  };

  while (m1) {
    int b = __builtin_ctzll(m1); m1 &= m1 - 1;
    evalc(__shfl(i1, b));
  }
  // lane-parallel full-tile rescan (tile with 2+ candidates): 2 chunks of 64 codes
  while (m2) {
    int b = __builtin_ctzll(m2); m2 &= m2 - 1;
    #pragma unroll 1
    for (int chunk = 0; chunk < 2; ++chunk) {
      const int c = b * 128 + chunk * 64 + lane;
      const float* wr = wgt + (size_t)c * DIM;
      double s = 0.0, nw = 0.0;
      #pragma unroll 4
      for (int d = 0; d < DIM; d += 4) {
        float4 wv = *(const float4*)(wr + d);
        float4 xw = *(const float4*)(xrow + d);   // lane-uniform broadcast
        s  += (double)wv.x * xw.x + (double)wv.y * xw.y + (double)wv.z * xw.z + (double)wv.w * xw.w;
        nw += (double)wv.x * wv.x + (double)wv.y * wv.y + (double)wv.z * wv.z + (double)wv.w * wv.w;
      }
      double sim = s / sqrt(nw + 1e-12);
      if (sim > bestv || (sim == bestv && c < besti)) { bestv = sim; besti = c; }
    }
  }
  // wave argmax (tie -> smallest index)
  #pragma unroll
  for (int off = 1; off < 64; off <<= 1) {
    double ov = __shfl_xor(bestv, off);
    int    oi = __shfl_xor(besti, off);
    if (ov > bestv || (ov == bestv && oi < besti)) { bestv = ov; besti = oi; }
  }
  if ((unsigned)besti >= KCB) besti = 0;    // hardening

  // fused: quantized gather + per-token loss partial
  const float* wr = wgt + (size_t)besti * DIM + lane * 8;
  float4 w0 = *(const float4*)wr;
  float4 w1 = *(const float4*)(wr + 4);
  float* o0 = out0 + (size_t)t * DIM + lane * 8;
  *(float4*)o0 = w0;
  *(float4*)(o0 + 4) = w1;
  double d2 = 0.0;
  double qv[8] = {w0.x, w0.y, w0.z, w0.w, w1.x, w1.y, w1.z, w1.w};
  #pragma unroll
  for (int j = 0; j < 8; ++j) { double d = qv[j] - xv[j]; d2 += d * d; }
  #pragma unroll
  for (int off = 1; off < 64; off <<= 1) d2 += __shfl_xor(d2, off);

  if (lane == 0) {
    lp[t] = (float)d2;
    out_idx[t] = (float)besti;
    int slot = atomicAdd(&cnt[besti], 1);
    if (slot < LISTCAP) list[besti * LISTCAP + slot] = t;
  }
}

// ---------------- K4: scalar reductions (pre-cs, n, loss) ----------------
__global__ __launch_bounds__(256) void k_scalars(const float* __restrict__ cs,
                                                 const int* __restrict__ cnt,
                                                 float* __restrict__ pre,
                                                 const float* __restrict__ lp,
                                                 double* __restrict__ nacc,
                                                 float* __restrict__ out1) {
  __shared__ double red[256];
  const int tid = threadIdx.x;
  double s = 0.0;
  for (int i = tid * 4; i < KCB; i += 1024) {
    float4 c4 = *(const float4*)(cs + i);
    int4   n4 = *(const int4*)(cnt + i);
    float p0 = c4.x * 0.99f + 0.01f * (float)n4.x;
    float p1 = c4.y * 0.99f + 0.01f * (float)n4.y;
    float p2 = c4.z * 0.99f + 0.01f * (float)n4.z;
    float p3 = c4.w * 0.99f + 0.01f * (float)n4.w;
    *(float4*)(pre + i) = make_float4(p0, p1, p2, p3);
    s += (double)p0 + (double)p1 + (double)p2 + (double)p3;
  }
  red[tid] = s; __syncthreads();
  for (int st = 128; st > 0; st >>= 1) { if (tid < st) red[tid] += red[tid + st]; __syncthreads(); }
  if (tid == 0) *nacc = red[0];
  __syncthreads();
  double l = 0.0;
  for (int i = tid * 4; i < NTOK; i += 1024) {
    float4 l4 = *(const float4*)(lp + i);
    l += (double)l4.x + (double)l4.y + (double)l4.z + (double)l4.w;
  }
  red[tid] = l; __syncthreads();
  for (int st = 128; st > 0; st >>= 1) { if (tid < st) red[tid] += red[tid + st]; __syncthreads(); }
  if (tid == 0) out1[0] = (float)(red[0] / (double)((size_t)NTOK * DIM));
}

// ---------------- K5: per-code gather-sum + EMA finalize (one block per code) ----------------
__global__ __launch_bounds__(256) void k_dw(const float* __restrict__ x,
                                            const float* __restrict__ ema_w,
                                            const int* __restrict__ cnt,
                                            const int* __restrict__ list,
                                            const float* __restrict__ pre,
                                            const double* __restrict__ nacc,
                                            float* __restrict__ out3,
                                            float* __restrict__ out4,
                                            float* __restrict__ out5) {
  const int c = blockIdx.x, tid = threadIdx.x;
  int m = cnt[c]; if (m > LISTCAP) m = LISTCAP;
  const double n = *nacc;
  const float csf = (float)(((double)pre[c] + 1e-5) / (n + (double)KCB * 1e-5) * n);
  const int d0 = tid * 2;
  double s0 = 0.0, s1 = 0.0;
  for (int j = 0; j < m; ++j) {
    int t = list[c * LISTCAP + j] & (NTOK - 1);
    float2 v = *(const float2*)(x + (size_t)t * DIM + d0);
    s0 += (double)v.x; s1 += (double)v.y;
  }
  const size_t e = (size_t)c * DIM + d0;
  float n0 = ema_w[e]     * 0.99f + 0.01f * (float)s0;
  float n1 = ema_w[e + 1] * 0.99f + 0.01f * (float)s1;
  out4[e] = n0;       out4[e + 1] = n1;
  out5[e] = n0 / csf; out5[e + 1] = n1 / csf;
  if (tid == 0) out3[c] = csf;
}

// ---------------- launch ----------------
extern "C" void kernel_launch(void* const* d_in, const int* in_sizes, int n_in,
                              void* d_out, int out_size, void* d_ws, size_t ws_size,
                              hipStream_t stream) {
  const float* x    = (const float*)d_in[0];   // [8,2048,512]
  const float* wgt  = (const float*)d_in[1];   // [8192,512]
  const float* cs   = (const float*)d_in[2];   // [8192]
  const float* emaw = (const float*)d_in[3];   // [8192,512]

  char* ws = (char*)d_ws;
  unsigned short* xn  = (unsigned short*)(ws + WS_XN);
  unsigned short* wn  = (unsigned short*)(ws + WS_WN);
  uint2* kv    = (uint2*)(ws + WS_KV);
  float* lp    = (float*)(ws + WS_LP);
  float* pre   = (float*)(ws + WS_PRE);
  double* nacc = (double*)(ws + WS_N);
  int*   cnt   = (int*)(ws + WS_CNT);
  int*   list  = (int*)(ws + WS_LIST);

  float* out0 = (float*)d_out;            // quantized_st [8388608]
  float* out1 = out0 + 8388608;           // loss [1]
  float* out2 = out1 + 1;                 // idx  [16384]
  float* out3 = out2 + NTOK;              // new_cs [8192]
  float* out4 = out3 + KCB;               // new_ema_w [4194304]
  float* out5 = out4 + (size_t)KCB * DIM; // new_weight [4194304]

  hipMemsetAsync(cnt, 0, KCB * sizeof(int), stream);

  k_normalize<<<NTOK + KCB, 256, 0, stream>>>(x, wgt, xn, wn);
  k_gemm_top2<<<dim3(32, 64), 512, 0, stream>>>(xn, wn, kv);
  k_select<<<NTOK / 4, 256, 0, stream>>>(x, wgt, kv, out0, out2, lp, cnt, list);
  k_scalars<<<1, 256, 0, stream>>>(cs, cnt, pre, lp, nacc, out1);
  k_dw<<<KCB, 256, 0, stream>>>(x, emaw, cnt, list, pre, nacc, out3, out4, out5);
}

// Round 2
// 347.456 us; speedup vs baseline: 1.0781x; 1.0781x over previous
//
#include <hip/hip_runtime.h>
#include <cstdint>
#include <cstddef>

// ---------------- problem constants ----------------
#define NTOK 16384          // 8*2048 tokens
#define DIM  512
#define KCB  8192           // codebook entries
#define MARGIN 6.0e-3f      // > worst-case bf16 screening error (validated R1-R5)
#define LISTCAP 512         // max tokens per code

typedef short s16x8 __attribute__((ext_vector_type(8)));   // 8 bf16 in 4 VGPRs
typedef float f32x4 __attribute__((ext_vector_type(4)));

// ---------------- workspace layout (bytes) ----------------
static const size_t WS_XN   = 0;           // ushort[NTOK*DIM]   bf16 normalized x  -> 16777216
static const size_t WS_WN   = 16777216;    // ushort[KCB*DIM]    bf16 normalized w  -> 25165824
static const size_t WS_KV   = 25165824;    // uint2[NTOK*64]     packed top2 keys   -> 33554432
static const size_t WS_LP   = 37748736;    // float[NTOK]        loss partials      -> 37814272
static const size_t WS_N    = 37847040;    // double[2]          nacc, lacc (zeroed)
static const size_t WS_CNT  = 37847296;    // int[KCB]           counts (zeroed)    -> 37880064
static const size_t WS_LIST = 37880064;    // int[KCB*LISTCAP]   token lists        -> 54657280

// ---------------- helpers ----------------
__device__ __forceinline__ void gl_lds16(const void* g, void* l) {
  __builtin_amdgcn_global_load_lds(
      (__attribute__((address_space(1))) void*)(uintptr_t)g,
      (__attribute__((address_space(3))) void*)(uint32_t)(uintptr_t)l,
      16, 0, 0);
}

__device__ __forceinline__ unsigned short f2bf(float f) {
  unsigned int u = __float_as_uint(f);
  u = (u + 0x7fffu + ((u >> 16) & 1u)) >> 16;   // RNE
  return (unsigned short)u;
}

// ---------------- K1: l2-normalize x and w rows into bf16 ----------------
__global__ __launch_bounds__(256) void k_normalize(const float* __restrict__ x,
                                                   const float* __restrict__ w,
                                                   unsigned short* __restrict__ xn,
                                                   unsigned short* __restrict__ wn) {
  const int row = blockIdx.x;
  const int tid = threadIdx.x, lane = tid & 63, wave = tid >> 6;
  const float* src;
  unsigned short* dst;
  if (row < NTOK) { src = x + (size_t)row * DIM;          dst = xn + (size_t)row * DIM; }
  else            { src = w + (size_t)(row - NTOK) * DIM; dst = wn + (size_t)(row - NTOK) * DIM; }
  const int e = tid * 2;
  float2 v = *(const float2*)(src + e);
  float ss = v.x * v.x + v.y * v.y;
  #pragma unroll
  for (int off = 32; off > 0; off >>= 1) ss += __shfl_xor(ss, off);
  __shared__ float red[4];
  if (lane == 0) red[wave] = ss;
  __syncthreads();
  const float s = red[0] + red[1] + red[2] + red[3];
  const float inv = rsqrtf(s + 1e-12f);
  unsigned int lo = f2bf(v.x * inv), hi = f2bf(v.y * inv);
  *(unsigned int*)(dst + e) = lo | (hi << 16);
}

// ---------------- K2: bf16 MFMA GEMM, block 128m x 256n, wave 64m x 128n ----------------
// (round-0 proven version: 894 TF effective, MfmaUtil ~40%, 0 bank conflicts)
// packed-key epilogue: key = (bits(sim+2.0) & ~0x7F) | (in-tile code 0..127)
// record = uint2{k1,k2} at kv[t*64 + tile], token-major
__global__ __launch_bounds__(256, 2) void k_gemm_top2(const unsigned short* __restrict__ xn,
                                                      const unsigned short* __restrict__ wn,
                                                      uint2* __restrict__ kv) {
  __shared__ __align__(16) unsigned short smA[128 * 64];   // 16 KB
  __shared__ __align__(16) unsigned short smB[256 * 64];   // 32 KB
  const int tid = threadIdx.x, wave = tid >> 6, lane = tid & 63;
  const int quad = lane >> 4, col = lane & 15;
  const int wave_m = (wave & 1) * 64, wave_n = (wave >> 1) * 128;
  const int n0 = blockIdx.x * 256, m0 = blockIdx.y * 128;

  const unsigned short* pA[4];
  const unsigned short* pB[8];
  unsigned short* dA[4];
  unsigned short* dB[8];
  #pragma unroll
  for (int i = 0; i < 4; ++i) {
    int s = wave * 256 + i * 64 + lane;
    int row = s >> 3, cg = (s & 7) ^ (row & 7);
    pA[i] = xn + (size_t)(m0 + row) * DIM + cg * 8;
    dA[i] = &smA[(size_t)(wave * 256 + i * 64) * 8];
  }
  #pragma unroll
  for (int i = 0; i < 8; ++i) {
    int s = wave * 512 + i * 64 + lane;
    int row = s >> 3, cg = (s & 7) ^ (row & 7);
    pB[i] = wn + (size_t)(n0 + row) * DIM + cg * 8;
    dB[i] = &smB[(size_t)(wave * 512 + i * 64) * 8];
  }

  int offA[4][2], offB[8][2];
  #pragma unroll
  for (int kbi = 0; kbi < 2; ++kbi) {
    int kb = kbi * 4 + quad;
    #pragma unroll
    for (int mi = 0; mi < 4; ++mi) {
      int row = wave_m + mi * 16 + col;
      offA[mi][kbi] = (row * 8 + (kb ^ (row & 7))) * 16;
    }
    #pragma unroll
    for (int ni = 0; ni < 8; ++ni) {
      int row = wave_n + ni * 16 + col;
      offB[ni][kbi] = (row * 8 + (kb ^ (row & 7))) * 16;
    }
  }

  f32x4 acc[4][8] = {};
  const char* sA = (const char*)smA;
  const char* sB = (const char*)smB;

  #pragma unroll 1
  for (int kt = 0; kt < 8; ++kt) {
    __syncthreads();
    #pragma unroll
    for (int i = 0; i < 4; ++i) { gl_lds16(pA[i], dA[i]); pA[i] += 64; }
    #pragma unroll
    for (int i = 0; i < 8; ++i) { gl_lds16(pB[i], dB[i]); pB[i] += 64; }
    __syncthreads();
    #pragma unroll
    for (int kbi = 0; kbi < 2; ++kbi) {
      s16x8 af[4], bfr[8];
      #pragma unroll
      for (int mi = 0; mi < 4; ++mi) af[mi]  = *(const s16x8*)(sA + offA[mi][kbi]);
      #pragma unroll
      for (int ni = 0; ni < 8; ++ni) bfr[ni] = *(const s16x8*)(sB + offB[ni][kbi]);
      #pragma unroll
      for (int mi = 0; mi < 4; ++mi)
        #pragma unroll
        for (int ni = 0; ni < 8; ++ni)
          acc[mi][ni] = __builtin_amdgcn_mfma_f32_16x16x32_bf16(af[mi], bfr[ni], acc[mi][ni], 0, 0, 0);
    }
  }

  // -------- epilogue: packed-key top2 over this wave's 128 codes --------
  const int tile = blockIdx.x * 2 + (wave >> 1);
  unsigned int rk1 = 0, rk2 = 0;
  #pragma unroll
  for (int mi = 0; mi < 4; ++mi) {
    #pragma unroll
    for (int r = 0; r < 4; ++r) {
      const int p = mi * 4 + r;
      unsigned int k1 = 0, k2 = 0;
      #pragma unroll
      for (int ni = 0; ni < 8; ++ni) {
        float vb = acc[mi][ni][r] + 2.0f;                 // biased positive -> uint order == float order
        unsigned int key = (__float_as_uint(vb) & ~0x7Fu) | (unsigned int)(ni * 16 + col);
        unsigned int mn = min(k1, key);
        k1 = max(k1, key);
        k2 = max(k2, mn);
      }
      #pragma unroll
      for (int off = 1; off < 16; off <<= 1) {
        unsigned int o1 = (unsigned int)__shfl_xor((int)k1, off);
        unsigned int o2 = (unsigned int)__shfl_xor((int)k2, off);
        unsigned int mn = min(k1, o1);
        k1 = max(k1, o1);
        k2 = max(max(k2, o2), mn);
      }
      if (col == p) { rk1 = k1; rk2 = k2; }               // lane-compact
    }
  }
  const int row = wave_m + (col >> 2) * 16 + quad * 4 + (col & 3);  // bijective over 64
  kv[(size_t)(m0 + row) * 64 + tile] = make_uint2(rk1, rk2);
}

// ---------------- K3: exact fp64 rescore -> idx, fused gather + loss + list ----------------
// 256 threads = 4 waves, one token per wave.
// NEW: single-candidate fast path — if exactly one tile-best is within MARGIN of the
// global bf16 max and no tile's 2nd-best is, the margin bound guarantees that candidate
// is the exact argmax (any exact tie/winner would lie within MARGIN in bf16 space).
// Skips all exact fp64 rescoring + the final 64-lane argmax reduce.
__global__ __launch_bounds__(256) void k_select(const float* __restrict__ x,
                                                const float* __restrict__ wgt,
                                                const uint2* __restrict__ kv,
                                                float* __restrict__ out0,
                                                float* __restrict__ out_idx,
                                                float* __restrict__ lp,
                                                int* __restrict__ cnt,
                                                int* __restrict__ list) {
  const int wave = threadIdx.x >> 6, lane = threadIdx.x & 63;
  const int t = blockIdx.x * 4 + wave;

  const uint2 kp = kv[(size_t)t * 64 + lane];
  const float v1 = __uint_as_float(kp.x);     // biased (+2.0), index bits add <=3e-5
  const float v2 = __uint_as_float(kp.y);
  const int   i1 = lane * 128 + (int)(kp.x & 0x7Fu);

  float gm = v1;
  #pragma unroll
  for (int off = 32; off > 0; off >>= 1) gm = fmaxf(gm, __shfl_xor(gm, off));
  const float thresh = gm - MARGIN;

  unsigned long long m1 = __ballot(v1 >= thresh);
  unsigned long long m2 = __ballot(v2 >= thresh);

  const float* xrow = x + (size_t)t * DIM;
  const float* xr = xrow + lane * 8;
  float4 x0 = *(const float4*)xr;
  float4 x1 = *(const float4*)(xr + 4);
  double xv[8] = {x0.x, x0.y, x0.z, x0.w, x1.x, x1.y, x1.z, x1.w};

  int besti;
  if (__popcll(m1) == 1 && m2 == 0ull) {
    // unambiguous bf16 winner -> exact winner
    besti = __shfl(i1, __builtin_ctzll(m1));
  } else {
    double bestv = -1e300; besti = 1 << 30;   // per-lane running best

    // wave-collective exact eval (result uniform across lanes)
    auto evalc = [&](int c) {
      const float* wr = wgt + (size_t)c * DIM + lane * 8;
      float4 w0 = *(const float4*)wr;
      float4 w1 = *(const float4*)(wr + 4);
      double s  = (double)w0.x * xv[0] + (double)w0.y * xv[1] + (double)w0.z * xv[2] + (double)w0.w * xv[3]
                + (double)w1.x * xv[4] + (double)w1.y * xv[5] + (double)w1.z * xv[6] + (double)w1.w * xv[7];
      double nw = (double)w0.x * w0.x + (double)w0.y * w0.y + (double)w0.z * w0.z + (double)w0.w * w0.w
                + (double)w1.x * w1.x + (double)w1.y * w1.y + (double)w1.z * w1.z + (double)w1.w * w1.w;
      #pragma unroll
      for (int off = 1; off < 64; off <<= 1) { s += __shfl_xor(s, off); nw += __shfl_xor(nw, off); }
      double sim = s / sqrt(nw + 1e-12);      // x-norm omitted: constant per token
      if (sim > bestv || (sim == bestv && c < besti)) { bestv = sim; besti = c; }
    };

    unsigned long long w1m = m1;
    while (w1m) {
      int b = __builtin_ctzll(w1m); w1m &= w1m - 1;
      evalc(__shfl(i1, b));
    }
    // lane-parallel full-tile rescan (tile with 2+ candidates): 2 chunks of 64 codes
    unsigned long long w2m = m2;
    while (w2m) {
      int b = __builtin_ctzll(w2m); w2m &= w2m - 1;
      #pragma unroll 1
      for (int chunk = 0; chunk < 2; ++chunk) {
        const int c = b * 128 + chunk * 64 + lane;
        const float* wr = wgt + (size_t)c * DIM;
        double s = 0.0, nw = 0.0;
        #pragma unroll 4
        for (int d = 0; d < DIM; d += 4) {
          float4 wv = *(const float4*)(wr + d);
          float4 xw = *(const float4*)(xrow + d);   // lane-uniform broadcast
          s  += (double)wv.x * xw.x + (double)wv.y * xw.y + (double)wv.z * xw.z + (double)wv.w * xw.w;
          nw += (double)wv.x * wv.x + (double)wv.y * wv.y + (double)wv.z * wv.z + (double)wv.w * wv.w;
        }
        double sim = s / sqrt(nw + 1e-12);
        if (sim > bestv || (sim == bestv && c < besti)) { bestv = sim; besti = c; }
      }
    }
    // wave argmax (tie -> smallest index)
    #pragma unroll
    for (int off = 1; off < 64; off <<= 1) {
      double ov = __shfl_xor(bestv, off);
      int    oi = __shfl_xor(besti, off);
      if (ov > bestv || (ov == bestv && oi < besti)) { bestv = ov; besti = oi; }
    }
  }
  if ((unsigned)besti >= KCB) besti = 0;    // hardening

  // fused: quantized gather + per-token loss partial
  const float* wr = wgt + (size_t)besti * DIM + lane * 8;
  float4 w0 = *(const float4*)wr;
  float4 w1 = *(const float4*)(wr + 4);
  float* o0 = out0 + (size_t)t * DIM + lane * 8;
  *(float4*)o0 = w0;
  *(float4*)(o0 + 4) = w1;
  double d2 = 0.0;
  double qv[8] = {w0.x, w0.y, w0.z, w0.w, w1.x, w1.y, w1.z, w1.w};
  #pragma unroll
  for (int j = 0; j < 8; ++j) { double d = qv[j] - xv[j]; d2 += d * d; }
  #pragma unroll
  for (int off = 1; off < 64; off <<= 1) d2 += __shfl_xor(d2, off);

  if (lane == 0) {
    lp[t] = (float)d2;
    out_idx[t] = (float)besti;
    int slot = atomicAdd(&cnt[besti], 1);
    if (slot < LISTCAP) list[besti * LISTCAP + slot] = t;
  }
}

// ---------------- K4: parallel partial sums (0.99*sum(cs) and sum(lp)) ----------------
// n = sum(cs*0.99 + 0.01*cnt) = 0.99*sum(cs) + 0.01*NTOK  (sum(cnt) == NTOK exactly).
// 32 blocks; one f64 atomicAdd per block per accumulator (negligible contention).
__global__ __launch_bounds__(256) void k_scalars(const float* __restrict__ cs,
                                                 const float* __restrict__ lp,
                                                 double* __restrict__ nacc,
                                                 double* __restrict__ lacc) {
  const int tid = threadIdx.x, b = blockIdx.x;
  const int wave = tid >> 6, lane = tid & 63;
  double s = (double)cs[b * 256 + tid];
  float2 l2 = *(const float2*)(lp + b * 512 + tid * 2);
  double l = (double)l2.x + (double)l2.y;
  #pragma unroll
  for (int off = 32; off > 0; off >>= 1) { s += __shfl_xor(s, off); l += __shfl_xor(l, off); }
  __shared__ double rs[4], rl[4];
  if (lane == 0) { rs[wave] = s; rl[wave] = l; }
  __syncthreads();
  if (tid == 0) {
    atomicAdd(nacc, 0.99 * (rs[0] + rs[1] + rs[2] + rs[3]));
    atomicAdd(lacc, rl[0] + rl[1] + rl[2] + rl[3]);
  }
}

// ---------------- K5: per-code gather-sum + EMA finalize (one block per code) ----------------
__global__ __launch_bounds__(256) void k_dw(const float* __restrict__ x,
                                            const float* __restrict__ ema_w,
                                            const float* __restrict__ cs,
                                            const int* __restrict__ cnt,
                                            const int* __restrict__ list,
                                            const double* __restrict__ nacc,
                                            const double* __restrict__ lacc,
                                            float* __restrict__ out1,
                                            float* __restrict__ out3,
                                            float* __restrict__ out4,
                                            float* __restrict__ out5) {
  const int c = blockIdx.x, tid = threadIdx.x;
  const int mtrue = cnt[c];
  const int m = mtrue > LISTCAP ? LISTCAP : mtrue;
  const double n = *nacc + 0.01 * (double)NTOK;
  const float prec = cs[c] * 0.99f + 0.01f * (float)mtrue;   // same f32 math as old pre[]
  const float csf = (float)(((double)prec + 1e-5) / (n + (double)KCB * 1e-5) * n);
  if (c == 0 && tid == 0) out1[0] = (float)(*lacc / (double)((size_t)NTOK * DIM));
  const int d0 = tid * 2;
  double s0 = 0.0, s1 = 0.0;
  for (int j = 0; j < m; ++j) {
    int t = list[c * LISTCAP + j] & (NTOK - 1);
    float2 v = *(const float2*)(x + (size_t)t * DIM + d0);
    s0 += (double)v.x; s1 += (double)v.y;
  }
  const size_t e = (size_t)c * DIM + d0;
  float n0 = ema_w[e]     * 0.99f + 0.01f * (float)s0;
  float n1 = ema_w[e + 1] * 0.99f + 0.01f * (float)s1;
  out4[e] = n0;       out4[e + 1] = n1;
  out5[e] = n0 / csf; out5[e + 1] = n1 / csf;
  if (tid == 0) out3[c] = csf;
}

// ---------------- launch ----------------
extern "C" void kernel_launch(void* const* d_in, const int* in_sizes, int n_in,
                              void* d_out, int out_size, void* d_ws, size_t ws_size,
                              hipStream_t stream) {
  const float* x    = (const float*)d_in[0];   // [8,2048,512]
  const float* wgt  = (const float*)d_in[1];   // [8192,512]
  const float* cs   = (const float*)d_in[2];   // [8192]
  const float* emaw = (const float*)d_in[3];   // [8192,512]

  char* ws = (char*)d_ws;
  unsigned short* xn  = (unsigned short*)(ws + WS_XN);
  unsigned short* wn  = (unsigned short*)(ws + WS_WN);
  uint2* kv    = (uint2*)(ws + WS_KV);
  float* lp    = (float*)(ws + WS_LP);
  double* nacc = (double*)(ws + WS_N);
  double* lacc = nacc + 1;
  int*   cnt   = (int*)(ws + WS_CNT);
  int*   list  = (int*)(ws + WS_LIST);

  float* out0 = (float*)d_out;            // quantized_st [8388608]
  float* out1 = out0 + 8388608;           // loss [1]
  float* out2 = out1 + 1;                 // idx  [16384]
  float* out3 = out2 + NTOK;              // new_cs [8192]
  float* out4 = out3 + KCB;               // new_ema_w [4194304]
  float* out5 = out4 + (size_t)KCB * DIM; // new_weight [4194304]

  hipMemsetAsync(cnt, 0, KCB * sizeof(int), stream);
  hipMemsetAsync(ws + WS_N, 0, 2 * sizeof(double), stream);

  k_normalize<<<NTOK + KCB, 256, 0, stream>>>(x, wgt, xn, wn);
  k_gemm_top2<<<dim3(32, 128), 256, 0, stream>>>(xn, wn, kv);
  k_select<<<NTOK / 4, 256, 0, stream>>>(x, wgt, kv, out0, out2, lp, cnt, list);
  k_scalars<<<32, 256, 0, stream>>>(cs, lp, nacc, lacc);
  k_dw<<<KCB, 256, 0, stream>>>(x, emaw, cs, cnt, list, nacc, lacc, out1, out3, out4, out5);
}

// Round 3
// 342.505 us; speedup vs baseline: 1.0937x; 1.0145x over previous
//
#include <hip/hip_runtime.h>
#include <cstdint>
#include <cstddef>

// ---------------- problem constants ----------------
#define NTOK 16384          // 8*2048 tokens
#define DIM  512
#define KCB  8192           // codebook entries
#define MARGIN 6.0e-3f      // > worst-case bf16 screening error (validated R1-R5)
#define LISTCAP 512         // max tokens per code

typedef short s16x8 __attribute__((ext_vector_type(8)));   // 8 bf16 in 4 VGPRs
typedef float f32x4 __attribute__((ext_vector_type(4)));

// ---------------- workspace layout (bytes) ----------------
static const size_t WS_XN   = 0;           // ushort[NTOK*DIM]   bf16 normalized x  -> 16777216
static const size_t WS_WN   = 16777216;    // ushort[KCB*DIM]    bf16 normalized w  -> 25165824
static const size_t WS_KV   = 25165824;    // uint2[NTOK*64]     packed top2 keys   -> 33554432
static const size_t WS_LP   = 37748736;    // float[NTOK]        loss partials      -> 37814272
static const size_t WS_CSP  = 37814272;    // double[128]        cs partial sums    -> 37815296
static const size_t WS_CNT  = 37847296;    // int[KCB]           counts (zeroed in K1)
static const size_t WS_LIST = 37880064;    // int[KCB*LISTCAP]   token lists        -> 54657280

// ---------------- helpers ----------------
__device__ __forceinline__ void gl_lds16(const void* g, void* l) {
  __builtin_amdgcn_global_load_lds(
      (__attribute__((address_space(1))) void*)(uintptr_t)g,
      (__attribute__((address_space(3))) void*)(uint32_t)(uintptr_t)l,
      16, 0, 0);
}

__device__ __forceinline__ unsigned int f2bf(float f) {
  unsigned int u = __float_as_uint(f);
  u = (u + 0x7fffu + ((u >> 16) & 1u)) >> 16;   // RNE
  return u;
}

// ---------------- K1: l2-normalize (one wave per row) + cnt zero + cs partials ----------------
// 6144 blocks x 256 threads = 4 waves/block, 1 row/wave, 32B/lane loads, no block barriers.
// Blocks [0,32): extra duty — zero cnt[8192] and write per-wave cs partial sums csp[128].
__global__ __launch_bounds__(256) void k_normalize(const float* __restrict__ x,
                                                   const float* __restrict__ w,
                                                   unsigned short* __restrict__ xn,
                                                   unsigned short* __restrict__ wn,
                                                   const float* __restrict__ cs,
                                                   double* __restrict__ csp,
                                                   int* __restrict__ cnt) {
  const int wave = threadIdx.x >> 6, lane = threadIdx.x & 63;
  const int row = blockIdx.x * 4 + wave;
  const float* src;
  unsigned short* dst;
  if (row < NTOK) { src = x + (size_t)row * DIM;          dst = xn + (size_t)row * DIM; }
  else            { src = w + (size_t)(row - NTOK) * DIM; dst = wn + (size_t)(row - NTOK) * DIM; }
  const float4 a = *(const float4*)(src + lane * 8);
  const float4 b = *(const float4*)(src + lane * 8 + 4);
  float ss = a.x * a.x + a.y * a.y + a.z * a.z + a.w * a.w
           + b.x * b.x + b.y * b.y + b.z * b.z + b.w * b.w;
  #pragma unroll
  for (int off = 32; off > 0; off >>= 1) ss += __shfl_xor(ss, off);
  const float inv = rsqrtf(ss + 1e-12f);
  uint4 o;
  o.x = f2bf(a.x * inv) | (f2bf(a.y * inv) << 16);
  o.y = f2bf(a.z * inv) | (f2bf(a.w * inv) << 16);
  o.z = f2bf(b.x * inv) | (f2bf(b.y * inv) << 16);
  o.w = f2bf(b.z * inv) | (f2bf(b.w * inv) << 16);
  *(uint4*)(dst + lane * 8) = o;

  // extra duty: 32 blocks x 256 threads cover KCB=8192
  if (blockIdx.x < 32) {
    const int i = blockIdx.x * 256 + threadIdx.x;
    cnt[i] = 0;
    double s = (double)cs[i];
    #pragma unroll
    for (int off = 32; off > 0; off >>= 1) s += __shfl_xor(s, off);
    if (lane == 0) csp[blockIdx.x * 4 + wave] = s;
  }
}

// ---------------- K2: bf16 MFMA GEMM, block 128m x 256n, wave 64m x 128n ----------------
// (round-0 proven version: 894 TF effective, MfmaUtil ~40%, 0 bank conflicts)
// packed-key epilogue: key = (bits(sim+2.0) & ~0x7F) | (in-tile code 0..127)
// record = uint2{k1,k2} at kv[t*64 + tile], token-major
__global__ __launch_bounds__(256, 2) void k_gemm_top2(const unsigned short* __restrict__ xn,
                                                      const unsigned short* __restrict__ wn,
                                                      uint2* __restrict__ kv) {
  __shared__ __align__(16) unsigned short smA[128 * 64];   // 16 KB
  __shared__ __align__(16) unsigned short smB[256 * 64];   // 32 KB
  const int tid = threadIdx.x, wave = tid >> 6, lane = tid & 63;
  const int quad = lane >> 4, col = lane & 15;
  const int wave_m = (wave & 1) * 64, wave_n = (wave >> 1) * 128;
  const int n0 = blockIdx.x * 256, m0 = blockIdx.y * 128;

  const unsigned short* pA[4];
  const unsigned short* pB[8];
  unsigned short* dA[4];
  unsigned short* dB[8];
  #pragma unroll
  for (int i = 0; i < 4; ++i) {
    int s = wave * 256 + i * 64 + lane;
    int row = s >> 3, cg = (s & 7) ^ (row & 7);
    pA[i] = xn + (size_t)(m0 + row) * DIM + cg * 8;
    dA[i] = &smA[(size_t)(wave * 256 + i * 64) * 8];
  }
  #pragma unroll
  for (int i = 0; i < 8; ++i) {
    int s = wave * 512 + i * 64 + lane;
    int row = s >> 3, cg = (s & 7) ^ (row & 7);
    pB[i] = wn + (size_t)(n0 + row) * DIM + cg * 8;
    dB[i] = &smB[(size_t)(wave * 512 + i * 64) * 8];
  }

  int offA[4][2], offB[8][2];
  #pragma unroll
  for (int kbi = 0; kbi < 2; ++kbi) {
    int kb = kbi * 4 + quad;
    #pragma unroll
    for (int mi = 0; mi < 4; ++mi) {
      int row = wave_m + mi * 16 + col;
      offA[mi][kbi] = (row * 8 + (kb ^ (row & 7))) * 16;
    }
    #pragma unroll
    for (int ni = 0; ni < 8; ++ni) {
      int row = wave_n + ni * 16 + col;
      offB[ni][kbi] = (row * 8 + (kb ^ (row & 7))) * 16;
    }
  }

  f32x4 acc[4][8] = {};
  const char* sA = (const char*)smA;
  const char* sB = (const char*)smB;

  #pragma unroll 1
  for (int kt = 0; kt < 8; ++kt) {
    __syncthreads();
    #pragma unroll
    for (int i = 0; i < 4; ++i) { gl_lds16(pA[i], dA[i]); pA[i] += 64; }
    #pragma unroll
    for (int i = 0; i < 8; ++i) { gl_lds16(pB[i], dB[i]); pB[i] += 64; }
    __syncthreads();
    #pragma unroll
    for (int kbi = 0; kbi < 2; ++kbi) {
      s16x8 af[4], bfr[8];
      #pragma unroll
      for (int mi = 0; mi < 4; ++mi) af[mi]  = *(const s16x8*)(sA + offA[mi][kbi]);
      #pragma unroll
      for (int ni = 0; ni < 8; ++ni) bfr[ni] = *(const s16x8*)(sB + offB[ni][kbi]);
      #pragma unroll
      for (int mi = 0; mi < 4; ++mi)
        #pragma unroll
        for (int ni = 0; ni < 8; ++ni)
          acc[mi][ni] = __builtin_amdgcn_mfma_f32_16x16x32_bf16(af[mi], bfr[ni], acc[mi][ni], 0, 0, 0);
    }
  }

  // -------- epilogue: packed-key top2 over this wave's 128 codes --------
  const int tile = blockIdx.x * 2 + (wave >> 1);
  unsigned int rk1 = 0, rk2 = 0;
  #pragma unroll
  for (int mi = 0; mi < 4; ++mi) {
    #pragma unroll
    for (int r = 0; r < 4; ++r) {
      const int p = mi * 4 + r;
      unsigned int k1 = 0, k2 = 0;
      #pragma unroll
      for (int ni = 0; ni < 8; ++ni) {
        float vb = acc[mi][ni][r] + 2.0f;                 // biased positive -> uint order == float order
        unsigned int key = (__float_as_uint(vb) & ~0x7Fu) | (unsigned int)(ni * 16 + col);
        unsigned int mn = min(k1, key);
        k1 = max(k1, key);
        k2 = max(k2, mn);
      }
      #pragma unroll
      for (int off = 1; off < 16; off <<= 1) {
        unsigned int o1 = (unsigned int)__shfl_xor((int)k1, off);
        unsigned int o2 = (unsigned int)__shfl_xor((int)k2, off);
        unsigned int mn = min(k1, o1);
        k1 = max(k1, o1);
        k2 = max(max(k2, o2), mn);
      }
      if (col == p) { rk1 = k1; rk2 = k2; }               // lane-compact
    }
  }
  const int row = wave_m + (col >> 2) * 16 + quad * 4 + (col & 3);  // bijective over 64
  kv[(size_t)(m0 + row) * 64 + tile] = make_uint2(rk1, rk2);
}

// ---------------- K3: exact fp64 rescore -> idx, fused gather + loss + list ----------------
// 256 threads = 4 waves, one token per wave.
// Fast path: single unambiguous bf16 winner beyond MARGIN -> exact winner, no rescoring.
__global__ __launch_bounds__(256) void k_select(const float* __restrict__ x,
                                                const float* __restrict__ wgt,
                                                const uint2* __restrict__ kv,
                                                float* __restrict__ out0,
                                                float* __restrict__ out_idx,
                                                float* __restrict__ lp,
                                                int* __restrict__ cnt,
                                                int* __restrict__ list) {
  const int wave = threadIdx.x >> 6, lane = threadIdx.x & 63;
  const int t = blockIdx.x * 4 + wave;

  const uint2 kp = kv[(size_t)t * 64 + lane];
  const float v1 = __uint_as_float(kp.x);     // biased (+2.0), index bits add <=3e-5
  const float v2 = __uint_as_float(kp.y);
  const int   i1 = lane * 128 + (int)(kp.x & 0x7Fu);

  float gm = v1;
  #pragma unroll
  for (int off = 32; off > 0; off >>= 1) gm = fmaxf(gm, __shfl_xor(gm, off));
  const float thresh = gm - MARGIN;

  unsigned long long m1 = __ballot(v1 >= thresh);
  unsigned long long m2 = __ballot(v2 >= thresh);

  const float* xrow = x + (size_t)t * DIM;
  const float* xr = xrow + lane * 8;
  float4 x0 = *(const float4*)xr;
  float4 x1 = *(const float4*)(xr + 4);
  double xv[8] = {x0.x, x0.y, x0.z, x0.w, x1.x, x1.y, x1.z, x1.w};

  int besti;
  if (__popcll(m1) == 1 && m2 == 0ull) {
    // unambiguous bf16 winner -> exact winner
    besti = __shfl(i1, __builtin_ctzll(m1));
  } else {
    double bestv = -1e300; besti = 1 << 30;   // per-lane running best

    // wave-collective exact eval (result uniform across lanes)
    auto evalc = [&](int c) {
      const float* wr = wgt + (size_t)c * DIM + lane * 8;
      float4 w0 = *(const float4*)wr;
      float4 w1 = *(const float4*)(wr + 4);
      double s  = (double)w0.x * xv[0] + (double)w0.y * xv[1] + (double)w0.z * xv[2] + (double)w0.w * xv[3]
                + (double)w1.x * xv[4] + (double)w1.y * xv[5] + (double)w1.z * xv[6] + (double)w1.w * xv[7];
      double nw = (double)w0.x * w0.x + (double)w0.y * w0.y + (double)w0.z * w0.z + (double)w0.w * w0.w
                + (double)w1.x * w1.x + (double)w1.y * w1.y + (double)w1.z * w1.z + (double)w1.w * w1.w;
      #pragma unroll
      for (int off = 1; off < 64; off <<= 1) { s += __shfl_xor(s, off); nw += __shfl_xor(nw, off); }
      double sim = s / sqrt(nw + 1e-12);      // x-norm omitted: constant per token
      if (sim > bestv || (sim == bestv && c < besti)) { bestv = sim; besti = c; }
    };

    unsigned long long w1m = m1;
    while (w1m) {
      int b = __builtin_ctzll(w1m); w1m &= w1m - 1;
      evalc(__shfl(i1, b));
    }
    // lane-parallel full-tile rescan (tile with 2+ candidates): 2 chunks of 64 codes
    unsigned long long w2m = m2;
    while (w2m) {
      int b = __builtin_ctzll(w2m); w2m &= w2m - 1;
      #pragma unroll 1
      for (int chunk = 0; chunk < 2; ++chunk) {
        const int c = b * 128 + chunk * 64 + lane;
        const float* wr = wgt + (size_t)c * DIM;
        double s = 0.0, nw = 0.0;
        #pragma unroll 4
        for (int d = 0; d < DIM; d += 4) {
          float4 wv = *(const float4*)(wr + d);
          float4 xw = *(const float4*)(xrow + d);   // lane-uniform broadcast
          s  += (double)wv.x * xw.x + (double)wv.y * xw.y + (double)wv.z * xw.z + (double)wv.w * xw.w;
          nw += (double)wv.x * wv.x + (double)wv.y * wv.y + (double)wv.z * wv.z + (double)wv.w * wv.w;
        }
        double sim = s / sqrt(nw + 1e-12);
        if (sim > bestv || (sim == bestv && c < besti)) { bestv = sim; besti = c; }
      }
    }
    // wave argmax (tie -> smallest index)
    #pragma unroll
    for (int off = 1; off < 64; off <<= 1) {
      double ov = __shfl_xor(bestv, off);
      int    oi = __shfl_xor(besti, off);
      if (ov > bestv || (ov == bestv && oi < besti)) { bestv = ov; besti = oi; }
    }
  }
  if ((unsigned)besti >= KCB) besti = 0;    // hardening

  // fused: quantized gather + per-token loss partial
  const float* wr = wgt + (size_t)besti * DIM + lane * 8;
  float4 w0 = *(const float4*)wr;
  float4 w1 = *(const float4*)(wr + 4);
  float* o0 = out0 + (size_t)t * DIM + lane * 8;
  *(float4*)o0 = w0;
  *(float4*)(o0 + 4) = w1;
  double d2 = 0.0;
  double qv[8] = {w0.x, w0.y, w0.z, w0.w, w1.x, w1.y, w1.z, w1.w};
  #pragma unroll
  for (int j = 0; j < 8; ++j) { double d = qv[j] - xv[j]; d2 += d * d; }
  #pragma unroll
  for (int off = 1; off < 64; off <<= 1) d2 += __shfl_xor(d2, off);

  if (lane == 0) {
    lp[t] = (float)d2;
    out_idx[t] = (float)besti;
    int slot = atomicAdd(&cnt[besti], 1);
    if (slot < LISTCAP) list[besti * LISTCAP + slot] = t;
  }
}

// ---------------- K4: per-code gather-sum + EMA finalize (one block per code) ----------------
// n reduced from csp[128] by wave 0 of every block (1 KB L2-hot); loss by block 0 only.
__global__ __launch_bounds__(256) void k_dw(const float* __restrict__ x,
                                            const float* __restrict__ ema_w,
                                            const float* __restrict__ cs,
                                            const int* __restrict__ cnt,
                                            const int* __restrict__ list,
                                            const double* __restrict__ csp,
                                            const float* __restrict__ lp,
                                            float* __restrict__ out1,
                                            float* __restrict__ out3,
                                            float* __restrict__ out4,
                                            float* __restrict__ out5) {
  const int c = blockIdx.x, tid = threadIdx.x;
  const int wave = tid >> 6, lane = tid & 63;
  __shared__ double sh_n;
  if (tid < 64) {
    double s = csp[tid] + csp[tid + 64];
    #pragma unroll
    for (int off = 32; off > 0; off >>= 1) s += __shfl_xor(s, off);
    if (tid == 0) sh_n = 0.99 * s + 0.01 * (double)NTOK;   // sum(cnt) == NTOK exactly
  }
  __syncthreads();
  const double n = sh_n;

  const int mtrue = cnt[c];
  const int m = mtrue > LISTCAP ? LISTCAP : mtrue;
  const float prec = cs[c] * 0.99f + 0.01f * (float)mtrue;   // same f32 math as reference pre
  const float csf = (float)(((double)prec + 1e-5) / (n + (double)KCB * 1e-5) * n);
  const int d0 = tid * 2;
  double s0 = 0.0, s1 = 0.0;
  for (int j = 0; j < m; ++j) {
    int t = list[c * LISTCAP + j] & (NTOK - 1);
    float2 v = *(const float2*)(x + (size_t)t * DIM + d0);
    s0 += (double)v.x; s1 += (double)v.y;
  }
  const size_t e = (size_t)c * DIM + d0;
  float n0 = ema_w[e]     * 0.99f + 0.01f * (float)s0;
  float n1 = ema_w[e + 1] * 0.99f + 0.01f * (float)s1;
  out4[e] = n0;       out4[e + 1] = n1;
  out5[e] = n0 / csf; out5[e + 1] = n1 / csf;
  if (tid == 0) out3[c] = csf;

  if (c == 0) {
    // loss reduction: 16384 floats, 256 threads x 16 float4
    double l = 0.0;
    for (int i = tid * 4; i < NTOK; i += 1024) {
      float4 l4 = *(const float4*)(lp + i);
      l += (double)l4.x + (double)l4.y + (double)l4.z + (double)l4.w;
    }
    #pragma unroll
    for (int off = 32; off > 0; off >>= 1) l += __shfl_xor(l, off);
    __shared__ double rl[4];
    if (lane == 0) rl[wave] = l;
    __syncthreads();
    if (tid == 0) out1[0] = (float)((rl[0] + rl[1] + rl[2] + rl[3]) / (double)((size_t)NTOK * DIM));
  }
}

// ---------------- launch ----------------
extern "C" void kernel_launch(void* const* d_in, const int* in_sizes, int n_in,
                              void* d_out, int out_size, void* d_ws, size_t ws_size,
                              hipStream_t stream) {
  const float* x    = (const float*)d_in[0];   // [8,2048,512]
  const float* wgt  = (const float*)d_in[1];   // [8192,512]
  const float* cs   = (const float*)d_in[2];   // [8192]
  const float* emaw = (const float*)d_in[3];   // [8192,512]

  char* ws = (char*)d_ws;
  unsigned short* xn  = (unsigned short*)(ws + WS_XN);
  unsigned short* wn  = (unsigned short*)(ws + WS_WN);
  uint2* kv    = (uint2*)(ws + WS_KV);
  float* lp    = (float*)(ws + WS_LP);
  double* csp  = (double*)(ws + WS_CSP);
  int*   cnt   = (int*)(ws + WS_CNT);
  int*   list  = (int*)(ws + WS_LIST);

  float* out0 = (float*)d_out;            // quantized_st [8388608]
  float* out1 = out0 + 8388608;           // loss [1]
  float* out2 = out1 + 1;                 // idx  [16384]
  float* out3 = out2 + NTOK;              // new_cs [8192]
  float* out4 = out3 + KCB;               // new_ema_w [4194304]
  float* out5 = out4 + (size_t)KCB * DIM; // new_weight [4194304]

  k_normalize<<<(NTOK + KCB) / 4, 256, 0, stream>>>(x, wgt, xn, wn, cs, csp, cnt);
  k_gemm_top2<<<dim3(32, 128), 256, 0, stream>>>(xn, wn, kv);
  k_select<<<NTOK / 4, 256, 0, stream>>>(x, wgt, kv, out0, out2, lp, cnt, list);
  k_dw<<<KCB, 256, 0, stream>>>(x, emaw, cs, cnt, list, csp, lp, out1, out3, out4, out5);
}